// Round 12
// baseline (155.504 us; speedup 1.0000x reference)
//
#include <hip/hip_runtime.h>
#include <hip/hip_bf16.h>

typedef __bf16 bf16_t;
typedef __bf16 bf16x8 __attribute__((ext_vector_type(8)));
typedef __bf16 bf16x4 __attribute__((ext_vector_type(4)));
typedef float f32x4 __attribute__((ext_vector_type(4)));

#define AS1 __attribute__((address_space(1)))
#define AS3 __attribute__((address_space(3)))

// ---------------------------------------------------------------------------
// Fused front-end, ONE dispatch (640 blocks x 256):
//   blocks 0..383   : bi_w fp32->bf16 (98304 chunks, exactly 1/thread)
//   blocks 384..639 : GEMM1  t = input_f32 @ fc_w_f32^T + fc_b  (bf16 out)
// ---------------------------------------------------------------------------
__global__ __launch_bounds__(256)
void frontend(const float* __restrict__ input, const float* __restrict__ fc_w,
              const float* __restrict__ fc_b, const float* __restrict__ bi_w,
              bf16_t* __restrict__ o_bw, bf16_t* __restrict__ t_out) {
    const int bid = blockIdx.x;
    const int tid = threadIdx.x;

    if (bid < 384) {
        const int k = bid * 256 + tid;
        float4 a = ((const float4*)bi_w)[k * 2];
        float4 b = ((const float4*)bi_w)[k * 2 + 1];
        bf16x8 v;
        v[0] = (bf16_t)a.x; v[1] = (bf16_t)a.y; v[2] = (bf16_t)a.z; v[3] = (bf16_t)a.w;
        v[4] = (bf16_t)b.x; v[5] = (bf16_t)b.y; v[6] = (bf16_t)b.z; v[7] = (bf16_t)b.w;
        ((bf16x8*)o_bw)[k] = v;
        return;
    }

    constexpr int K = 768, N = 256;
    constexpr int MR = 4, NR = 2;
    __shared__ bf16_t As[128 * 64];
    __shared__ bf16_t Bs[64 * 64];

    const int g = bid - 384;
    const int mblk = g & 63, nblk = g >> 6;
    const int lane = tid & 63;
    const int wave = tid >> 6;

    const float* Ab = input + (long)mblk * 128 * K;
    const float* Bf = fc_w + (long)nblk * 64 * K;

    f32x4 acc[MR][NR] = {};

    const int wrow = (wave >> 1) * 64;
    const int wcol = (wave & 1) * 32;
    const int lrow = lane & 15;
    const int kgrp = lane >> 4;

    for (int k0 = 0; k0 < K; k0 += 64) {
#pragma unroll
        for (int it = 0; it < 8; ++it) {
            const int c = it * 256 + tid;
            const int row = c >> 4, c4 = c & 15;
            f32x4 v = *(const f32x4*)(Ab + (long)row * K + k0 + c4 * 4);
            bf16x4 w = { (bf16_t)v[0], (bf16_t)v[1], (bf16_t)v[2], (bf16_t)v[3] };
            *(bf16x4*)(As + row * 64 + c4 * 4) = w;
        }
#pragma unroll
        for (int it = 0; it < 4; ++it) {
            const int c = it * 256 + tid;
            const int row = c >> 4, c4 = c & 15;
            f32x4 v = *(const f32x4*)(Bf + (long)row * K + k0 + c4 * 4);
            bf16x4 w = { (bf16_t)v[0], (bf16_t)v[1], (bf16_t)v[2], (bf16_t)v[3] };
            *(bf16x4*)(Bs + row * 64 + c4 * 4) = w;
        }
        __syncthreads();

#pragma unroll
        for (int kk = 0; kk < 64; kk += 32) {
            const int koff = kk + kgrp * 8;
            bf16x8 af[MR], bfr[NR];
#pragma unroll
            for (int m = 0; m < MR; ++m)
                af[m] = *(const bf16x8*)(As + (wrow + m * 16 + lrow) * 64 + koff);
#pragma unroll
            for (int n = 0; n < NR; ++n)
                bfr[n] = *(const bf16x8*)(Bs + (wcol + lrow * NR + n) * 64 + koff);
#pragma unroll
            for (int m = 0; m < MR; ++m)
#pragma unroll
                for (int n = 0; n < NR; ++n)
                    acc[m][n] = __builtin_amdgcn_mfma_f32_16x16x32_bf16(af[m], bfr[n], acc[m][n], 0, 0, 0);
        }
        __syncthreads();
    }

    typedef float fvec __attribute__((ext_vector_type(NR)));
    typedef bf16_t bvec __attribute__((ext_vector_type(NR)));
    const long rbase = (long)mblk * 128 + wrow + kgrp * 4;
    const long cb0   = (long)nblk * 64 + wcol + lrow * NR;
    fvec bv = *(const fvec*)(fc_b + cb0);
#pragma unroll
    for (int m = 0; m < MR; ++m)
#pragma unroll
        for (int j = 0; j < 4; ++j) {
            bvec v;
#pragma unroll
            for (int n = 0; n < NR; ++n) v[n] = (bf16_t)(acc[m][n][j] + bv[n]);
            *(bvec*)(t_out + (rbase + m * 16 + j) * N + cb0) = v;
        }
}

// ---------------------------------------------------------------------------
// 8-phase 256x256 GEMM, K=256 — GEMM2 only (compute-bound, bf16 out).
// ---------------------------------------------------------------------------
template <int EPI, int XCD, int NMB, int NNB>
__global__ __launch_bounds__(512, 2)
void gemm8p(const bf16_t* __restrict__ A, const bf16_t* __restrict__ Bm,
            void* __restrict__ Cv, const float* __restrict__ bias,
            int N, long sA, long sB, long sC) {
    constexpr int K = 256;
    extern __shared__ bf16_t lds[];

    const int tid  = threadIdx.x;
    const int lane = tid & 63;
    const int wave = tid >> 6;
    const int wm = wave >> 2, wn = wave & 3;
    const int lrow = lane & 15, kgrp = lane >> 4;

    int mblk, nblk, bz;
    {
        int L = blockIdx.x;
        if (XCD) { bz = L & 7; int w = L >> 3; nblk = w % NNB; mblk = w / NNB; }
        else     { bz = 0;     mblk = L % NMB; nblk = L / NMB; }
    }

    const bf16_t* Ab = A + (long)bz * sA + (long)mblk * 256 * K;
    const bf16_t* Bb = Bm + (long)bz * sB + (long)nblk * 256 * K;

    const int c0 = tid, c1 = 512 + tid;
    const int r0 = c0 >> 3, r1 = c1 >> 3;
    const int ca0 = (c0 & 7) ^ (r0 & 7),        ca1 = (c1 & 7) ^ (r1 & 7);
    const int cb0 = (c0 & 7) ^ ((r0 >> 2) & 7), cb1 = (c1 & 7) ^ ((r1 >> 2) & 7);

    auto stageA = [&](int t, int h) {
        const bf16_t* s0 = Ab + (long)(h * 128 + r0) * K + t * 64 + ca0 * 8;
        const bf16_t* s1 = Ab + (long)(h * 128 + r1) * K + t * 64 + ca1 * 8;
        bf16_t* d = lds + ((t & 1) * 2 + h) * 8192;
        __builtin_amdgcn_global_load_lds((const AS1 void*)s0, (AS3 void*)(d + c0 * 8), 16, 0, 0);
        __builtin_amdgcn_global_load_lds((const AS1 void*)s1, (AS3 void*)(d + c1 * 8), 16, 0, 0);
    };
    auto stageB = [&](int t, int h) {
        const bf16_t* s0 = Bb + (long)(h * 128 + r0) * K + t * 64 + cb0 * 8;
        const bf16_t* s1 = Bb + (long)(h * 128 + r1) * K + t * 64 + cb1 * 8;
        bf16_t* d = lds + 32768 + ((t & 1) * 2 + h) * 8192;
        __builtin_amdgcn_global_load_lds((const AS1 void*)s0, (AS3 void*)(d + c0 * 8), 16, 0, 0);
        __builtin_amdgcn_global_load_lds((const AS1 void*)s1, (AS3 void*)(d + c1 * 8), 16, 0, 0);
    };
    auto ldA = [&](int t, int mf, int kk) -> bf16x8 {
        const int row = mf * 16 + lrow;
        const int col = (kk * 32 + kgrp * 8) ^ ((row & 7) << 3);
        return *(const bf16x8*)(lds + ((t & 1) * 2 + wm) * 8192 + row * 64 + col);
    };
    auto ldB = [&](int t, int g, int kk) -> bf16x8 {
        const int row = (wn & 1) * 64 + lrow * 4 + g;
        const int col = (kk * 32 + kgrp * 8) ^ (((row >> 2) & 7) << 3);
        return *(const bf16x8*)(lds + 32768 + ((t & 1) * 2 + (wn >> 1)) * 8192 + row * 64 + col);
    };

    f32x4 acc[8][4] = {};
    bf16x8 bfr[4][2];

    stageA(0, 0); stageA(0, 1); stageB(0, 0); stageB(0, 1); stageB(1, 0); stageB(1, 1);
    asm volatile("s_waitcnt vmcnt(4)" ::: "memory");
    __builtin_amdgcn_s_barrier();

#pragma unroll
    for (int i = 0; i < 2; ++i) {
#pragma unroll
        for (int p = 0; p < 8; ++p) {
            const int q = p & 3;
            const int t = 2 * i + (p >> 2);
            bf16x8 af[2][2];
            if (q == 0) {
#pragma unroll
                for (int g = 0; g < 4; ++g) { bfr[g][0] = ldB(t, g, 0); bfr[g][1] = ldB(t, g, 1); }
            }
#pragma unroll
            for (int mm = 0; mm < 2; ++mm) { af[mm][0] = ldA(t, 2 * q + mm, 0); af[mm][1] = ldA(t, 2 * q + mm, 1); }

            if (p == 0) stageA(2 * i + 1, 0);
            else if (p == 1) stageA(2 * i + 1, 1);
            else if (p == 2) { if (2 * i + 2 < 4) stageB(2 * i + 2, 0); }
            else if (p == 3) { if (2 * i + 2 < 4) stageB(2 * i + 2, 1); }
            else if (p == 4) { if (2 * i + 2 < 4) stageA(2 * i + 2, 0); }
            else if (p == 5) { if (2 * i + 2 < 4) stageA(2 * i + 2, 1); }
            else if (p == 6) { if (2 * i + 3 < 4) stageB(2 * i + 3, 0); }
            else             { if (2 * i + 3 < 4) stageB(2 * i + 3, 1); }

            __builtin_amdgcn_s_barrier();
            asm volatile("s_waitcnt lgkmcnt(0)" ::: "memory");
            __builtin_amdgcn_s_setprio(1);
#pragma unroll
            for (int mm = 0; mm < 2; ++mm)
#pragma unroll
                for (int g = 0; g < 4; ++g)
#pragma unroll
                    for (int kk = 0; kk < 2; ++kk)
                        acc[2 * q + mm][g] = __builtin_amdgcn_mfma_f32_16x16x32_bf16(
                            af[mm][kk], bfr[g][kk], acc[2 * q + mm][g], 0, 0, 0);
            __builtin_amdgcn_s_setprio(0);

            if (p == 3) {
                if (2 * i + 2 < 4) asm volatile("s_waitcnt vmcnt(4)" ::: "memory");
                else               asm volatile("s_waitcnt vmcnt(0)" ::: "memory");
            } else if (p == 7) {
                if (2 * i + 2 < 4) asm volatile("s_waitcnt vmcnt(4)" ::: "memory");
            }
            __builtin_amdgcn_s_barrier();
        }
    }

    const long rb = (long)mblk * 256 + wm * 128 + kgrp * 4;
    const long cb = (long)nblk * 256 + wn * 64 + lrow * 4;
    if constexpr (EPI == 0) {
        float* C = (float*)Cv + (long)bz * sC;
#pragma unroll
        for (int m = 0; m < 8; ++m)
#pragma unroll
            for (int j = 0; j < 4; ++j) {
                f32x4 v = { acc[m][0][j], acc[m][1][j], acc[m][2][j], acc[m][3][j] };
                __builtin_nontemporal_store(v, (f32x4*)(C + (rb + m * 16 + j) * N + cb));
            }
    } else {
        bf16_t* C = (bf16_t*)Cv;
        f32x4 bv = *(const f32x4*)(bias + (int)(cb & 255));
#pragma unroll
        for (int m = 0; m < 8; ++m)
#pragma unroll
            for (int j = 0; j < 4; ++j) {
                bf16x4 v;
#pragma unroll
                for (int g = 0; g < 4; ++g) v[g] = (bf16_t)(acc[m][g][j] + bv[g]);
                *(bf16x4*)(C + (rb + m * 16 + j) * N + cb) = v;
            }
    }
}

// ---------------------------------------------------------------------------
// GEMM3 (R6 structure, A/B: CACHED stores instead of NT): out_b = bl_b @
// t_b^T, fp32 out. 192x128 tile, BK=64 dbuf, 256 threads, 80 KB LDS -> 2
// blocks/CU. Reads are L2-hot (bz = L&7 pins each batch to one XCD). This
// round tests whether NT stores (L2-bypass) were capping the write stream vs
// cached streaming stores (fillBuffer hits 6.8 TB/s with cached stores).
// ---------------------------------------------------------------------------
template <int NNB>
__global__ __launch_bounds__(256, 2)
void gemm3k(const bf16_t* __restrict__ A, const bf16_t* __restrict__ Bm,
            float* __restrict__ C, long sA, long sB, long sC) {
    constexpr int K = 256, BM = 192, BN = 128;
    extern __shared__ bf16_t lds[];   // A: buf*12288 ; B: 24576 + buf*8192

    const int tid  = threadIdx.x;
    const int lane = tid & 63;
    const int wave = tid >> 6;
    const int wm = wave >> 1, wn = wave & 1;
    const int lrow = lane & 15, kgrp = lane >> 4;

    const int L = blockIdx.x;
    const int bz = L & 7;
    const int w = L >> 3;
    const int nblk = w & (NNB - 1), mblk = w / NNB;

    const bf16_t* Ab = A + (long)bz * sA + (long)mblk * BM * K;
    const bf16_t* Bb = Bm + (long)bz * sB + (long)nblk * BN * K;

    auto stage = [&](int t) {
        const int buf = t & 1;
#pragma unroll
        for (int it = 0; it < 6; ++it) {          // A: 192x64 = 1536 chunks
            const int c = it * 256 + tid, row = c >> 3;
            const int sa = (c & 7) ^ (row & 7);
            __builtin_amdgcn_global_load_lds(
                (const AS1 void*)(Ab + (long)row * K + t * 64 + sa * 8),
                (AS3 void*)(lds + buf * 12288 + c * 8), 16, 0, 0);
        }
#pragma unroll
        for (int it = 0; it < 4; ++it) {          // B: 128x64 = 1024 chunks
            const int c = it * 256 + tid, row = c >> 3;
            const int sb = (c & 7) ^ ((row >> 2) & 7);
            __builtin_amdgcn_global_load_lds(
                (const AS1 void*)(Bb + (long)row * K + t * 64 + sb * 8),
                (AS3 void*)(lds + 24576 + buf * 8192 + c * 8), 16, 0, 0);
        }
    };

    f32x4 acc[6][4] = {};

    stage(0);
    __syncthreads();

#pragma unroll
    for (int t = 0; t < 4; ++t) {
        if (t < 3) stage(t + 1);
        const int buf = t & 1;
        bf16x8 af[6][2], bfr[4][2];
#pragma unroll
        for (int m = 0; m < 6; ++m) {
            const int r = wm * 96 + m * 16 + lrow;
#pragma unroll
            for (int kk = 0; kk < 2; ++kk)
                af[m][kk] = *(const bf16x8*)(lds + buf * 12288 + r * 64 +
                                             ((kk * 32 + kgrp * 8) ^ ((r & 7) << 3)));
        }
#pragma unroll
        for (int g = 0; g < 4; ++g) {
            const int r = wn * 64 + lrow * 4 + g;
#pragma unroll
            for (int kk = 0; kk < 2; ++kk)
                bfr[g][kk] = *(const bf16x8*)(lds + 24576 + buf * 8192 + r * 64 +
                                              ((kk * 32 + kgrp * 8) ^ (((r >> 2) & 7) << 3)));
        }
        __builtin_amdgcn_s_setprio(1);
#pragma unroll
        for (int m = 0; m < 6; ++m)
#pragma unroll
            for (int g = 0; g < 4; ++g)
#pragma unroll
                for (int kk = 0; kk < 2; ++kk)
                    acc[m][g] = __builtin_amdgcn_mfma_f32_16x16x32_bf16(
                        af[m][kk], bfr[g][kk], acc[m][g], 0, 0, 0);
        __builtin_amdgcn_s_setprio(0);
        __syncthreads();
    }

    float* Cb = C + (long)bz * sC;
    const long rb = (long)mblk * BM + wm * 96 + kgrp * 4;
    const long cb = (long)nblk * BN + wn * 64 + lrow * 4;
#pragma unroll
    for (int m = 0; m < 6; ++m)
#pragma unroll
        for (int j = 0; j < 4; ++j) {
            f32x4 v = { acc[m][0][j], acc[m][1][j], acc[m][2][j], acc[m][3][j] };
            *(f32x4*)(Cb + (rb + m * 16 + j) * 1024 + cb) = v;   // cached store
        }
}

// ---------------------------------------------------------------------------
// B=8, S=1024, IN=768, E=256, L=12. 3 dispatches total.
// ---------------------------------------------------------------------------
extern "C" void kernel_launch(void* const* d_in, const int* in_sizes, int n_in,
                              void* d_out, int out_size, void* d_ws, size_t ws_size,
                              hipStream_t stream) {
    const float* input = (const float*)d_in[0];
    const float* fc_w  = (const float*)d_in[1];
    const float* fc_b  = (const float*)d_in[2];
    const float* bi_w  = (const float*)d_in[3];
    const float* bias  = (const float*)d_in[4];

    char* ws = (char*)d_ws;
    bf16_t* wbi = (bf16_t*)(ws);             // 3072*256*2 = 1,572,864
    bf16_t* t   = (bf16_t*)(ws + 1572864);   // 8192*256*2 = 4,194,304
    bf16_t* bl  = (bf16_t*)(ws + 5767168);   // 8192*3072*2 = 50,331,648

    // Front-end: bi_w cvt (384 blocks) + GEMM1 w/ fused A,B cvt (256 blocks)
    frontend<<<dim3(640), dim3(256), 0, stream>>>(
        input, fc_w, fc_b, bi_w, wbi, t);

    // GEMM2: bl = t @ wbi^T + bias[col&255]  (8-phase 256^2; 384 blocks)
    gemm8p<2, 0, 32, 12><<<dim3(384), dim3(512), 131072, stream>>>(
        t, wbi, (void*)bl, bias, 3072, 0L, 0L, 0L);

    // GEMM3 (batched x8): 192x128 tile, 4096 blocks, 2/CU, CACHED stores
    gemm3k<8><<<dim3(4096), dim3(256), 81920, stream>>>(
        bl, t, (float*)d_out,
        (long)12288 * 256, (long)1024 * 256, (long)12288 * 1024);
}

// Round 13
// 127.354 us; speedup vs baseline: 1.2210x; 1.2210x over previous
//
#include <hip/hip_runtime.h>
#include <hip/hip_bf16.h>

typedef __bf16 bf16_t;
typedef __bf16 bf16x8 __attribute__((ext_vector_type(8)));
typedef __bf16 bf16x4 __attribute__((ext_vector_type(4)));
typedef float f32x4 __attribute__((ext_vector_type(4)));

#define AS1 __attribute__((address_space(1)))
#define AS3 __attribute__((address_space(3)))

// ---------------------------------------------------------------------------
// Fused front-end, ONE dispatch (640 blocks x 256):
//   blocks 0..383   : bi_w fp32->bf16 (98304 chunks, exactly 1/thread)
//   blocks 384..639 : GEMM1  t = input_f32 @ fc_w_f32^T + fc_b  (bf16 out)
// ---------------------------------------------------------------------------
__global__ __launch_bounds__(256)
void frontend(const float* __restrict__ input, const float* __restrict__ fc_w,
              const float* __restrict__ fc_b, const float* __restrict__ bi_w,
              bf16_t* __restrict__ o_bw, bf16_t* __restrict__ t_out) {
    const int bid = blockIdx.x;
    const int tid = threadIdx.x;

    if (bid < 384) {
        const int k = bid * 256 + tid;
        float4 a = ((const float4*)bi_w)[k * 2];
        float4 b = ((const float4*)bi_w)[k * 2 + 1];
        bf16x8 v;
        v[0] = (bf16_t)a.x; v[1] = (bf16_t)a.y; v[2] = (bf16_t)a.z; v[3] = (bf16_t)a.w;
        v[4] = (bf16_t)b.x; v[5] = (bf16_t)b.y; v[6] = (bf16_t)b.z; v[7] = (bf16_t)b.w;
        ((bf16x8*)o_bw)[k] = v;
        return;
    }

    constexpr int K = 768, N = 256;
    constexpr int MR = 4, NR = 2;
    __shared__ bf16_t As[128 * 64];
    __shared__ bf16_t Bs[64 * 64];

    const int g = bid - 384;
    const int mblk = g & 63, nblk = g >> 6;
    const int lane = tid & 63;
    const int wave = tid >> 6;

    const float* Ab = input + (long)mblk * 128 * K;
    const float* Bf = fc_w + (long)nblk * 64 * K;

    f32x4 acc[MR][NR] = {};

    const int wrow = (wave >> 1) * 64;
    const int wcol = (wave & 1) * 32;
    const int lrow = lane & 15;
    const int kgrp = lane >> 4;

    for (int k0 = 0; k0 < K; k0 += 64) {
#pragma unroll
        for (int it = 0; it < 8; ++it) {
            const int c = it * 256 + tid;
            const int row = c >> 4, c4 = c & 15;
            f32x4 v = *(const f32x4*)(Ab + (long)row * K + k0 + c4 * 4);
            bf16x4 w = { (bf16_t)v[0], (bf16_t)v[1], (bf16_t)v[2], (bf16_t)v[3] };
            *(bf16x4*)(As + row * 64 + c4 * 4) = w;
        }
#pragma unroll
        for (int it = 0; it < 4; ++it) {
            const int c = it * 256 + tid;
            const int row = c >> 4, c4 = c & 15;
            f32x4 v = *(const f32x4*)(Bf + (long)row * K + k0 + c4 * 4);
            bf16x4 w = { (bf16_t)v[0], (bf16_t)v[1], (bf16_t)v[2], (bf16_t)v[3] };
            *(bf16x4*)(Bs + row * 64 + c4 * 4) = w;
        }
        __syncthreads();

#pragma unroll
        for (int kk = 0; kk < 64; kk += 32) {
            const int koff = kk + kgrp * 8;
            bf16x8 af[MR], bfr[NR];
#pragma unroll
            for (int m = 0; m < MR; ++m)
                af[m] = *(const bf16x8*)(As + (wrow + m * 16 + lrow) * 64 + koff);
#pragma unroll
            for (int n = 0; n < NR; ++n)
                bfr[n] = *(const bf16x8*)(Bs + (wcol + lrow * NR + n) * 64 + koff);
#pragma unroll
            for (int m = 0; m < MR; ++m)
#pragma unroll
                for (int n = 0; n < NR; ++n)
                    acc[m][n] = __builtin_amdgcn_mfma_f32_16x16x32_bf16(af[m], bfr[n], acc[m][n], 0, 0, 0);
        }
        __syncthreads();
    }

    typedef float fvec __attribute__((ext_vector_type(NR)));
    typedef bf16_t bvec __attribute__((ext_vector_type(NR)));
    const long rbase = (long)mblk * 128 + wrow + kgrp * 4;
    const long cb0   = (long)nblk * 64 + wcol + lrow * NR;
    fvec bv = *(const fvec*)(fc_b + cb0);
#pragma unroll
    for (int m = 0; m < MR; ++m)
#pragma unroll
        for (int j = 0; j < 4; ++j) {
            bvec v;
#pragma unroll
            for (int n = 0; n < NR; ++n) v[n] = (bf16_t)(acc[m][n][j] + bv[n]);
            *(bvec*)(t_out + (rbase + m * 16 + j) * N + cb0) = v;
        }
}

// ---------------------------------------------------------------------------
// 8-phase 256x256 GEMM, K=256 — GEMM2 only (compute-bound, bf16 out).
// ---------------------------------------------------------------------------
template <int EPI, int XCD, int NMB, int NNB>
__global__ __launch_bounds__(512, 2)
void gemm8p(const bf16_t* __restrict__ A, const bf16_t* __restrict__ Bm,
            void* __restrict__ Cv, const float* __restrict__ bias,
            int N, long sA, long sB, long sC) {
    constexpr int K = 256;
    extern __shared__ bf16_t lds[];

    const int tid  = threadIdx.x;
    const int lane = tid & 63;
    const int wave = tid >> 6;
    const int wm = wave >> 2, wn = wave & 3;
    const int lrow = lane & 15, kgrp = lane >> 4;

    int mblk, nblk, bz;
    {
        int L = blockIdx.x;
        if (XCD) { bz = L & 7; int w = L >> 3; nblk = w % NNB; mblk = w / NNB; }
        else     { bz = 0;     mblk = L % NMB; nblk = L / NMB; }
    }

    const bf16_t* Ab = A + (long)bz * sA + (long)mblk * 256 * K;
    const bf16_t* Bb = Bm + (long)bz * sB + (long)nblk * 256 * K;

    const int c0 = tid, c1 = 512 + tid;
    const int r0 = c0 >> 3, r1 = c1 >> 3;
    const int ca0 = (c0 & 7) ^ (r0 & 7),        ca1 = (c1 & 7) ^ (r1 & 7);
    const int cb0 = (c0 & 7) ^ ((r0 >> 2) & 7), cb1 = (c1 & 7) ^ ((r1 >> 2) & 7);

    auto stageA = [&](int t, int h) {
        const bf16_t* s0 = Ab + (long)(h * 128 + r0) * K + t * 64 + ca0 * 8;
        const bf16_t* s1 = Ab + (long)(h * 128 + r1) * K + t * 64 + ca1 * 8;
        bf16_t* d = lds + ((t & 1) * 2 + h) * 8192;
        __builtin_amdgcn_global_load_lds((const AS1 void*)s0, (AS3 void*)(d + c0 * 8), 16, 0, 0);
        __builtin_amdgcn_global_load_lds((const AS1 void*)s1, (AS3 void*)(d + c1 * 8), 16, 0, 0);
    };
    auto stageB = [&](int t, int h) {
        const bf16_t* s0 = Bb + (long)(h * 128 + r0) * K + t * 64 + cb0 * 8;
        const bf16_t* s1 = Bb + (long)(h * 128 + r1) * K + t * 64 + cb1 * 8;
        bf16_t* d = lds + 32768 + ((t & 1) * 2 + h) * 8192;
        __builtin_amdgcn_global_load_lds((const AS1 void*)s0, (AS3 void*)(d + c0 * 8), 16, 0, 0);
        __builtin_amdgcn_global_load_lds((const AS1 void*)s1, (AS3 void*)(d + c1 * 8), 16, 0, 0);
    };
    auto ldA = [&](int t, int mf, int kk) -> bf16x8 {
        const int row = mf * 16 + lrow;
        const int col = (kk * 32 + kgrp * 8) ^ ((row & 7) << 3);
        return *(const bf16x8*)(lds + ((t & 1) * 2 + wm) * 8192 + row * 64 + col);
    };
    auto ldB = [&](int t, int g, int kk) -> bf16x8 {
        const int row = (wn & 1) * 64 + lrow * 4 + g;
        const int col = (kk * 32 + kgrp * 8) ^ (((row >> 2) & 7) << 3);
        return *(const bf16x8*)(lds + 32768 + ((t & 1) * 2 + (wn >> 1)) * 8192 + row * 64 + col);
    };

    f32x4 acc[8][4] = {};
    bf16x8 bfr[4][2];

    stageA(0, 0); stageA(0, 1); stageB(0, 0); stageB(0, 1); stageB(1, 0); stageB(1, 1);
    asm volatile("s_waitcnt vmcnt(4)" ::: "memory");
    __builtin_amdgcn_s_barrier();

#pragma unroll
    for (int i = 0; i < 2; ++i) {
#pragma unroll
        for (int p = 0; p < 8; ++p) {
            const int q = p & 3;
            const int t = 2 * i + (p >> 2);
            bf16x8 af[2][2];
            if (q == 0) {
#pragma unroll
                for (int g = 0; g < 4; ++g) { bfr[g][0] = ldB(t, g, 0); bfr[g][1] = ldB(t, g, 1); }
            }
#pragma unroll
            for (int mm = 0; mm < 2; ++mm) { af[mm][0] = ldA(t, 2 * q + mm, 0); af[mm][1] = ldA(t, 2 * q + mm, 1); }

            if (p == 0) stageA(2 * i + 1, 0);
            else if (p == 1) stageA(2 * i + 1, 1);
            else if (p == 2) { if (2 * i + 2 < 4) stageB(2 * i + 2, 0); }
            else if (p == 3) { if (2 * i + 2 < 4) stageB(2 * i + 2, 1); }
            else if (p == 4) { if (2 * i + 2 < 4) stageA(2 * i + 2, 0); }
            else if (p == 5) { if (2 * i + 2 < 4) stageA(2 * i + 2, 1); }
            else if (p == 6) { if (2 * i + 3 < 4) stageB(2 * i + 3, 0); }
            else             { if (2 * i + 3 < 4) stageB(2 * i + 3, 1); }

            __builtin_amdgcn_s_barrier();
            asm volatile("s_waitcnt lgkmcnt(0)" ::: "memory");
            __builtin_amdgcn_s_setprio(1);
#pragma unroll
            for (int mm = 0; mm < 2; ++mm)
#pragma unroll
                for (int g = 0; g < 4; ++g)
#pragma unroll
                    for (int kk = 0; kk < 2; ++kk)
                        acc[2 * q + mm][g] = __builtin_amdgcn_mfma_f32_16x16x32_bf16(
                            af[mm][kk], bfr[g][kk], acc[2 * q + mm][g], 0, 0, 0);
            __builtin_amdgcn_s_setprio(0);

            if (p == 3) {
                if (2 * i + 2 < 4) asm volatile("s_waitcnt vmcnt(4)" ::: "memory");
                else               asm volatile("s_waitcnt vmcnt(0)" ::: "memory");
            } else if (p == 7) {
                if (2 * i + 2 < 4) asm volatile("s_waitcnt vmcnt(4)" ::: "memory");
            }
            __builtin_amdgcn_s_barrier();
        }
    }

    const long rb = (long)mblk * 256 + wm * 128 + kgrp * 4;
    const long cb = (long)nblk * 256 + wn * 64 + lrow * 4;
    if constexpr (EPI == 0) {
        float* C = (float*)Cv + (long)bz * sC;
#pragma unroll
        for (int m = 0; m < 8; ++m)
#pragma unroll
            for (int j = 0; j < 4; ++j) {
                f32x4 v = { acc[m][0][j], acc[m][1][j], acc[m][2][j], acc[m][3][j] };
                __builtin_nontemporal_store(v, (f32x4*)(C + (rb + m * 16 + j) * N + cb));
            }
    } else {
        bf16_t* C = (bf16_t*)Cv;
        f32x4 bv = *(const f32x4*)(bias + (int)(cb & 255));
#pragma unroll
        for (int m = 0; m < 8; ++m)
#pragma unroll
            for (int j = 0; j < 4; ++j) {
                bf16x4 v;
#pragma unroll
                for (int g = 0; g < 4; ++g) v[g] = (bf16_t)(acc[m][g][j] + bv[g]);
                *(bf16x4*)(C + (rb + m * 16 + j) * N + cb) = v;
            }
    }
}

// ---------------------------------------------------------------------------
// GEMM3 at 3 blocks/CU: out_b = bl_b[12288,256] @ t_b[1024,256]^T, fp32 NT.
// 192x128 tile, BK=32 double-buffered -> LDS 40 KB; __launch_bounds__(256,3)
// caps VGPR so 3 blocks/CU co-reside (vs 2 at BK=64/80KB). Mechanism: more
// co-resident blocks overlap each other's NT-store drains (R4->R6 showed
// 1->2 was -10us). 8 K-steps, R6-proven sync: stage(t+1) -> ds_read(t) ->
// 24 MFMA -> __syncthreads. Swizzle keys (2-bit, 4 chunks/row): A row&3,
// B (row>>2)&3 -> 4-way LDS read conflict (acceptable; LDS off critical path).
// ---------------------------------------------------------------------------
template <int NNB>
__global__ __launch_bounds__(256, 3)
void gemm3m(const bf16_t* __restrict__ A, const bf16_t* __restrict__ Bm,
            float* __restrict__ C, long sA, long sB, long sC) {
    constexpr int K = 256, BM = 192, BN = 128;
    extern __shared__ bf16_t lds[];   // A: buf*6144 (2x12KB); B: 12288 + buf*4096 (2x8KB)

    const int tid  = threadIdx.x;
    const int lane = tid & 63;
    const int wave = tid >> 6;
    const int wm = wave >> 1, wn = wave & 1;
    const int lrow = lane & 15, kgrp = lane >> 4;

    const int L = blockIdx.x;
    const int bz = L & 7;
    const int w = L >> 3;
    const int nblk = w & (NNB - 1), mblk = w / NNB;

    const bf16_t* Ab = A + (long)bz * sA + (long)mblk * BM * K;
    const bf16_t* Bb = Bm + (long)bz * sB + (long)nblk * BN * K;

    auto stage = [&](int t) {
        const int buf = t & 1;
#pragma unroll
        for (int it = 0; it < 3; ++it) {          // A: 192x32 = 768 chunks
            const int c = it * 256 + tid, row = c >> 2;
            const int sa = (c & 3) ^ (row & 3);
            __builtin_amdgcn_global_load_lds(
                (const AS1 void*)(Ab + (long)row * K + t * 32 + sa * 8),
                (AS3 void*)(lds + buf * 6144 + c * 8), 16, 0, 0);
        }
#pragma unroll
        for (int it = 0; it < 2; ++it) {          // B: 128x32 = 512 chunks
            const int c = it * 256 + tid, row = c >> 2;
            const int sb = (c & 3) ^ ((row >> 2) & 3);
            __builtin_amdgcn_global_load_lds(
                (const AS1 void*)(Bb + (long)row * K + t * 32 + sb * 8),
                (AS3 void*)(lds + 12288 + buf * 4096 + c * 8), 16, 0, 0);
        }
    };

    f32x4 acc[6][4] = {};

    stage(0);
    __syncthreads();

#pragma unroll
    for (int t = 0; t < 8; ++t) {
        if (t < 7) stage(t + 1);
        const int buf = t & 1;
        bf16x8 af[6], bfr[4];
#pragma unroll
        for (int m = 0; m < 6; ++m) {
            const int r = wm * 96 + m * 16 + lrow;
            af[m] = *(const bf16x8*)(lds + buf * 6144 + r * 32 + ((kgrp ^ (r & 3)) * 8));
        }
#pragma unroll
        for (int g = 0; g < 4; ++g) {
            const int r = wn * 64 + lrow * 4 + g;
            bfr[g] = *(const bf16x8*)(lds + 12288 + buf * 4096 + r * 32 +
                                      ((kgrp ^ ((r >> 2) & 3)) * 8));
        }
        __builtin_amdgcn_s_setprio(1);
#pragma unroll
        for (int m = 0; m < 6; ++m)
#pragma unroll
            for (int g = 0; g < 4; ++g)
                acc[m][g] = __builtin_amdgcn_mfma_f32_16x16x32_bf16(
                    af[m], bfr[g], acc[m][g], 0, 0, 0);
        __builtin_amdgcn_s_setprio(0);
        __syncthreads();
    }

    float* Cb = C + (long)bz * sC;
    const long rb = (long)mblk * BM + wm * 96 + kgrp * 4;
    const long cb = (long)nblk * BN + wn * 64 + lrow * 4;
#pragma unroll
    for (int m = 0; m < 6; ++m)
#pragma unroll
        for (int j = 0; j < 4; ++j) {
            f32x4 v = { acc[m][0][j], acc[m][1][j], acc[m][2][j], acc[m][3][j] };
            __builtin_nontemporal_store(v, (f32x4*)(Cb + (rb + m * 16 + j) * 1024 + cb));
        }
}

// ---------------------------------------------------------------------------
// B=8, S=1024, IN=768, E=256, L=12. 3 dispatches total.
// ---------------------------------------------------------------------------
extern "C" void kernel_launch(void* const* d_in, const int* in_sizes, int n_in,
                              void* d_out, int out_size, void* d_ws, size_t ws_size,
                              hipStream_t stream) {
    const float* input = (const float*)d_in[0];
    const float* fc_w  = (const float*)d_in[1];
    const float* fc_b  = (const float*)d_in[2];
    const float* bi_w  = (const float*)d_in[3];
    const float* bias  = (const float*)d_in[4];

    char* ws = (char*)d_ws;
    bf16_t* wbi = (bf16_t*)(ws);             // 3072*256*2 = 1,572,864
    bf16_t* t   = (bf16_t*)(ws + 1572864);   // 8192*256*2 = 4,194,304
    bf16_t* bl  = (bf16_t*)(ws + 5767168);   // 8192*3072*2 = 50,331,648

    // Front-end: bi_w cvt (384 blocks) + GEMM1 w/ fused A,B cvt (256 blocks)
    frontend<<<dim3(640), dim3(256), 0, stream>>>(
        input, fc_w, fc_b, bi_w, wbi, t);

    // GEMM2: bl = t @ wbi^T + bias[col&255]  (8-phase 256^2; 384 blocks)
    gemm8p<2, 0, 32, 12><<<dim3(384), dim3(512), 131072, stream>>>(
        t, wbi, (void*)bl, bias, 3072, 0L, 0L, 0L);

    // GEMM3 (batched x8): 192x128 tile, BK=32, 40 KB LDS -> 3 blocks/CU, NT
    gemm3m<8><<<dim3(4096), dim3(256), 40960, stream>>>(
        bl, t, (float*)d_out,
        (long)12288 * 256, (long)1024 * 256, (long)12288 * 1024);
}

// Round 14
// 123.405 us; speedup vs baseline: 1.2601x; 1.0320x over previous
//
#include <hip/hip_runtime.h>
#include <hip/hip_bf16.h>

typedef __bf16 bf16_t;
typedef __bf16 bf16x8 __attribute__((ext_vector_type(8)));
typedef __bf16 bf16x4 __attribute__((ext_vector_type(4)));
typedef float f32x4 __attribute__((ext_vector_type(4)));

#define AS1 __attribute__((address_space(1)))
#define AS3 __attribute__((address_space(3)))

// ---------------------------------------------------------------------------
// Fused front-end, ONE dispatch (640 blocks x 256):
//   blocks 0..383   : bi_w fp32->bf16 (98304 chunks, exactly 1/thread)
//   blocks 384..639 : GEMM1  t = input_f32 @ fc_w_f32^T + fc_b  (bf16 out)
// ---------------------------------------------------------------------------
__global__ __launch_bounds__(256)
void frontend(const float* __restrict__ input, const float* __restrict__ fc_w,
              const float* __restrict__ fc_b, const float* __restrict__ bi_w,
              bf16_t* __restrict__ o_bw, bf16_t* __restrict__ t_out) {
    const int bid = blockIdx.x;
    const int tid = threadIdx.x;

    if (bid < 384) {
        const int k = bid * 256 + tid;
        float4 a = ((const float4*)bi_w)[k * 2];
        float4 b = ((const float4*)bi_w)[k * 2 + 1];
        bf16x8 v;
        v[0] = (bf16_t)a.x; v[1] = (bf16_t)a.y; v[2] = (bf16_t)a.z; v[3] = (bf16_t)a.w;
        v[4] = (bf16_t)b.x; v[5] = (bf16_t)b.y; v[6] = (bf16_t)b.z; v[7] = (bf16_t)b.w;
        ((bf16x8*)o_bw)[k] = v;
        return;
    }

    constexpr int K = 768, N = 256;
    constexpr int MR = 4, NR = 2;
    __shared__ bf16_t As[128 * 64];
    __shared__ bf16_t Bs[64 * 64];

    const int g = bid - 384;
    const int mblk = g & 63, nblk = g >> 6;
    const int lane = tid & 63;
    const int wave = tid >> 6;

    const float* Ab = input + (long)mblk * 128 * K;
    const float* Bf = fc_w + (long)nblk * 64 * K;

    f32x4 acc[MR][NR] = {};

    const int wrow = (wave >> 1) * 64;
    const int wcol = (wave & 1) * 32;
    const int lrow = lane & 15;
    const int kgrp = lane >> 4;

    for (int k0 = 0; k0 < K; k0 += 64) {
#pragma unroll
        for (int it = 0; it < 8; ++it) {
            const int c = it * 256 + tid;
            const int row = c >> 4, c4 = c & 15;
            f32x4 v = *(const f32x4*)(Ab + (long)row * K + k0 + c4 * 4);
            bf16x4 w = { (bf16_t)v[0], (bf16_t)v[1], (bf16_t)v[2], (bf16_t)v[3] };
            *(bf16x4*)(As + row * 64 + c4 * 4) = w;
        }
#pragma unroll
        for (int it = 0; it < 4; ++it) {
            const int c = it * 256 + tid;
            const int row = c >> 4, c4 = c & 15;
            f32x4 v = *(const f32x4*)(Bf + (long)row * K + k0 + c4 * 4);
            bf16x4 w = { (bf16_t)v[0], (bf16_t)v[1], (bf16_t)v[2], (bf16_t)v[3] };
            *(bf16x4*)(Bs + row * 64 + c4 * 4) = w;
        }
        __syncthreads();

#pragma unroll
        for (int kk = 0; kk < 64; kk += 32) {
            const int koff = kk + kgrp * 8;
            bf16x8 af[MR], bfr[NR];
#pragma unroll
            for (int m = 0; m < MR; ++m)
                af[m] = *(const bf16x8*)(As + (wrow + m * 16 + lrow) * 64 + koff);
#pragma unroll
            for (int n = 0; n < NR; ++n)
                bfr[n] = *(const bf16x8*)(Bs + (wcol + lrow * NR + n) * 64 + koff);
#pragma unroll
            for (int m = 0; m < MR; ++m)
#pragma unroll
                for (int n = 0; n < NR; ++n)
                    acc[m][n] = __builtin_amdgcn_mfma_f32_16x16x32_bf16(af[m], bfr[n], acc[m][n], 0, 0, 0);
        }
        __syncthreads();
    }

    typedef float fvec __attribute__((ext_vector_type(NR)));
    typedef bf16_t bvec __attribute__((ext_vector_type(NR)));
    const long rbase = (long)mblk * 128 + wrow + kgrp * 4;
    const long cb0   = (long)nblk * 64 + wcol + lrow * NR;
    fvec bv = *(const fvec*)(fc_b + cb0);
#pragma unroll
    for (int m = 0; m < MR; ++m)
#pragma unroll
        for (int j = 0; j < 4; ++j) {
            bvec v;
#pragma unroll
            for (int n = 0; n < NR; ++n) v[n] = (bf16_t)(acc[m][n][j] + bv[n]);
            *(bvec*)(t_out + (rbase + m * 16 + j) * N + cb0) = v;
        }
}

// ---------------------------------------------------------------------------
// 8-phase 256x256 GEMM, K=256 — GEMM2 only (compute-bound, bf16 out).
// ---------------------------------------------------------------------------
template <int EPI, int XCD, int NMB, int NNB>
__global__ __launch_bounds__(512, 2)
void gemm8p(const bf16_t* __restrict__ A, const bf16_t* __restrict__ Bm,
            void* __restrict__ Cv, const float* __restrict__ bias,
            int N, long sA, long sB, long sC) {
    constexpr int K = 256;
    extern __shared__ bf16_t lds[];

    const int tid  = threadIdx.x;
    const int lane = tid & 63;
    const int wave = tid >> 6;
    const int wm = wave >> 2, wn = wave & 3;
    const int lrow = lane & 15, kgrp = lane >> 4;

    int mblk, nblk, bz;
    {
        int L = blockIdx.x;
        if (XCD) { bz = L & 7; int w = L >> 3; nblk = w % NNB; mblk = w / NNB; }
        else     { bz = 0;     mblk = L % NMB; nblk = L / NMB; }
    }

    const bf16_t* Ab = A + (long)bz * sA + (long)mblk * 256 * K;
    const bf16_t* Bb = Bm + (long)bz * sB + (long)nblk * 256 * K;

    const int c0 = tid, c1 = 512 + tid;
    const int r0 = c0 >> 3, r1 = c1 >> 3;
    const int ca0 = (c0 & 7) ^ (r0 & 7),        ca1 = (c1 & 7) ^ (r1 & 7);
    const int cb0 = (c0 & 7) ^ ((r0 >> 2) & 7), cb1 = (c1 & 7) ^ ((r1 >> 2) & 7);

    auto stageA = [&](int t, int h) {
        const bf16_t* s0 = Ab + (long)(h * 128 + r0) * K + t * 64 + ca0 * 8;
        const bf16_t* s1 = Ab + (long)(h * 128 + r1) * K + t * 64 + ca1 * 8;
        bf16_t* d = lds + ((t & 1) * 2 + h) * 8192;
        __builtin_amdgcn_global_load_lds((const AS1 void*)s0, (AS3 void*)(d + c0 * 8), 16, 0, 0);
        __builtin_amdgcn_global_load_lds((const AS1 void*)s1, (AS3 void*)(d + c1 * 8), 16, 0, 0);
    };
    auto stageB = [&](int t, int h) {
        const bf16_t* s0 = Bb + (long)(h * 128 + r0) * K + t * 64 + cb0 * 8;
        const bf16_t* s1 = Bb + (long)(h * 128 + r1) * K + t * 64 + cb1 * 8;
        bf16_t* d = lds + 32768 + ((t & 1) * 2 + h) * 8192;
        __builtin_amdgcn_global_load_lds((const AS1 void*)s0, (AS3 void*)(d + c0 * 8), 16, 0, 0);
        __builtin_amdgcn_global_load_lds((const AS1 void*)s1, (AS3 void*)(d + c1 * 8), 16, 0, 0);
    };
    auto ldA = [&](int t, int mf, int kk) -> bf16x8 {
        const int row = mf * 16 + lrow;
        const int col = (kk * 32 + kgrp * 8) ^ ((row & 7) << 3);
        return *(const bf16x8*)(lds + ((t & 1) * 2 + wm) * 8192 + row * 64 + col);
    };
    auto ldB = [&](int t, int g, int kk) -> bf16x8 {
        const int row = (wn & 1) * 64 + lrow * 4 + g;
        const int col = (kk * 32 + kgrp * 8) ^ (((row >> 2) & 7) << 3);
        return *(const bf16x8*)(lds + 32768 + ((t & 1) * 2 + (wn >> 1)) * 8192 + row * 64 + col);
    };

    f32x4 acc[8][4] = {};
    bf16x8 bfr[4][2];

    stageA(0, 0); stageA(0, 1); stageB(0, 0); stageB(0, 1); stageB(1, 0); stageB(1, 1);
    asm volatile("s_waitcnt vmcnt(4)" ::: "memory");
    __builtin_amdgcn_s_barrier();

#pragma unroll
    for (int i = 0; i < 2; ++i) {
#pragma unroll
        for (int p = 0; p < 8; ++p) {
            const int q = p & 3;
            const int t = 2 * i + (p >> 2);
            bf16x8 af[2][2];
            if (q == 0) {
#pragma unroll
                for (int g = 0; g < 4; ++g) { bfr[g][0] = ldB(t, g, 0); bfr[g][1] = ldB(t, g, 1); }
            }
#pragma unroll
            for (int mm = 0; mm < 2; ++mm) { af[mm][0] = ldA(t, 2 * q + mm, 0); af[mm][1] = ldA(t, 2 * q + mm, 1); }

            if (p == 0) stageA(2 * i + 1, 0);
            else if (p == 1) stageA(2 * i + 1, 1);
            else if (p == 2) { if (2 * i + 2 < 4) stageB(2 * i + 2, 0); }
            else if (p == 3) { if (2 * i + 2 < 4) stageB(2 * i + 2, 1); }
            else if (p == 4) { if (2 * i + 2 < 4) stageA(2 * i + 2, 0); }
            else if (p == 5) { if (2 * i + 2 < 4) stageA(2 * i + 2, 1); }
            else if (p == 6) { if (2 * i + 3 < 4) stageB(2 * i + 3, 0); }
            else             { if (2 * i + 3 < 4) stageB(2 * i + 3, 1); }

            __builtin_amdgcn_s_barrier();
            asm volatile("s_waitcnt lgkmcnt(0)" ::: "memory");
            __builtin_amdgcn_s_setprio(1);
#pragma unroll
            for (int mm = 0; mm < 2; ++mm)
#pragma unroll
                for (int g = 0; g < 4; ++g)
#pragma unroll
                    for (int kk = 0; kk < 2; ++kk)
                        acc[2 * q + mm][g] = __builtin_amdgcn_mfma_f32_16x16x32_bf16(
                            af[mm][kk], bfr[g][kk], acc[2 * q + mm][g], 0, 0, 0);
            __builtin_amdgcn_s_setprio(0);

            if (p == 3) {
                if (2 * i + 2 < 4) asm volatile("s_waitcnt vmcnt(4)" ::: "memory");
                else               asm volatile("s_waitcnt vmcnt(0)" ::: "memory");
            } else if (p == 7) {
                if (2 * i + 2 < 4) asm volatile("s_waitcnt vmcnt(4)" ::: "memory");
            }
            __builtin_amdgcn_s_barrier();
        }
    }

    const long rb = (long)mblk * 256 + wm * 128 + kgrp * 4;
    const long cb = (long)nblk * 256 + wn * 64 + lrow * 4;
    if constexpr (EPI == 0) {
        float* C = (float*)Cv + (long)bz * sC;
#pragma unroll
        for (int m = 0; m < 8; ++m)
#pragma unroll
            for (int j = 0; j < 4; ++j) {
                f32x4 v = { acc[m][0][j], acc[m][1][j], acc[m][2][j], acc[m][3][j] };
                __builtin_nontemporal_store(v, (f32x4*)(C + (rb + m * 16 + j) * N + cb));
            }
    } else {
        bf16_t* C = (bf16_t*)Cv;
        f32x4 bv = *(const f32x4*)(bias + (int)(cb & 255));
#pragma unroll
        for (int m = 0; m < 8; ++m)
#pragma unroll
            for (int j = 0; j < 4; ++j) {
                bf16x4 v;
#pragma unroll
                for (int g = 0; g < 4; ++g) v[g] = (bf16_t)(acc[m][g][j] + bv[g]);
                *(bf16x4*)(C + (rb + m * 16 + j) * N + cb) = v;
            }
    }
}

// ---------------------------------------------------------------------------
// GEMM3 (best measured form): out_b = bl_b[12288,256] @ t_b[1024,256]^T,
// fp32 NT out. 192x128 tile, BK=64 dbuf, 256 threads, 80 KB LDS -> 2
// blocks/CU; stage(t+1) -> ds_read(t) -> 48 MFMA -> __syncthreads.
// Write-bound plateau: 402 MB fp32 at ~4.7 TB/s effective (mixed-stream).
// Tested & rejected: counted-vmcnt, persistent-panel, continuous-store,
// cached stores (+32us), 1 blk/CU (+10us), 3 blk/CU (+4us).
// ---------------------------------------------------------------------------
template <int NNB>
__global__ __launch_bounds__(256, 2)
void gemm3k(const bf16_t* __restrict__ A, const bf16_t* __restrict__ Bm,
            float* __restrict__ C, long sA, long sB, long sC) {
    constexpr int K = 256, BM = 192, BN = 128;
    extern __shared__ bf16_t lds[];   // A: buf*12288 ; B: 24576 + buf*8192

    const int tid  = threadIdx.x;
    const int lane = tid & 63;
    const int wave = tid >> 6;
    const int wm = wave >> 1, wn = wave & 1;
    const int lrow = lane & 15, kgrp = lane >> 4;

    const int L = blockIdx.x;
    const int bz = L & 7;
    const int w = L >> 3;
    const int nblk = w & (NNB - 1), mblk = w / NNB;

    const bf16_t* Ab = A + (long)bz * sA + (long)mblk * BM * K;
    const bf16_t* Bb = Bm + (long)bz * sB + (long)nblk * BN * K;

    auto stage = [&](int t) {
        const int buf = t & 1;
#pragma unroll
        for (int it = 0; it < 6; ++it) {          // A: 192x64 = 1536 chunks
            const int c = it * 256 + tid, row = c >> 3;
            const int sa = (c & 7) ^ (row & 7);
            __builtin_amdgcn_global_load_lds(
                (const AS1 void*)(Ab + (long)row * K + t * 64 + sa * 8),
                (AS3 void*)(lds + buf * 12288 + c * 8), 16, 0, 0);
        }
#pragma unroll
        for (int it = 0; it < 4; ++it) {          // B: 128x64 = 1024 chunks
            const int c = it * 256 + tid, row = c >> 3;
            const int sb = (c & 7) ^ ((row >> 2) & 7);
            __builtin_amdgcn_global_load_lds(
                (const AS1 void*)(Bb + (long)row * K + t * 64 + sb * 8),
                (AS3 void*)(lds + 24576 + buf * 8192 + c * 8), 16, 0, 0);
        }
    };

    f32x4 acc[6][4] = {};

    stage(0);
    __syncthreads();

#pragma unroll
    for (int t = 0; t < 4; ++t) {
        if (t < 3) stage(t + 1);
        const int buf = t & 1;
        bf16x8 af[6][2], bfr[4][2];
#pragma unroll
        for (int m = 0; m < 6; ++m) {
            const int r = wm * 96 + m * 16 + lrow;
#pragma unroll
            for (int kk = 0; kk < 2; ++kk)
                af[m][kk] = *(const bf16x8*)(lds + buf * 12288 + r * 64 +
                                             ((kk * 32 + kgrp * 8) ^ ((r & 7) << 3)));
        }
#pragma unroll
        for (int g = 0; g < 4; ++g) {
            const int r = wn * 64 + lrow * 4 + g;
#pragma unroll
            for (int kk = 0; kk < 2; ++kk)
                bfr[g][kk] = *(const bf16x8*)(lds + 24576 + buf * 8192 + r * 64 +
                                              ((kk * 32 + kgrp * 8) ^ (((r >> 2) & 7) << 3)));
        }
        __builtin_amdgcn_s_setprio(1);
#pragma unroll
        for (int m = 0; m < 6; ++m)
#pragma unroll
            for (int g = 0; g < 4; ++g)
#pragma unroll
                for (int kk = 0; kk < 2; ++kk)
                    acc[m][g] = __builtin_amdgcn_mfma_f32_16x16x32_bf16(
                        af[m][kk], bfr[g][kk], acc[m][g], 0, 0, 0);
        __builtin_amdgcn_s_setprio(0);
        __syncthreads();
    }

    float* Cb = C + (long)bz * sC;
    const long rb = (long)mblk * BM + wm * 96 + kgrp * 4;
    const long cb = (long)nblk * BN + wn * 64 + lrow * 4;
#pragma unroll
    for (int m = 0; m < 6; ++m)
#pragma unroll
        for (int j = 0; j < 4; ++j) {
            f32x4 v = { acc[m][0][j], acc[m][1][j], acc[m][2][j], acc[m][3][j] };
            __builtin_nontemporal_store(v, (f32x4*)(Cb + (rb + m * 16 + j) * 1024 + cb));
        }
}

// ---------------------------------------------------------------------------
// B=8, S=1024, IN=768, E=256, L=12. 3 dispatches total.
// ---------------------------------------------------------------------------
extern "C" void kernel_launch(void* const* d_in, const int* in_sizes, int n_in,
                              void* d_out, int out_size, void* d_ws, size_t ws_size,
                              hipStream_t stream) {
    const float* input = (const float*)d_in[0];
    const float* fc_w  = (const float*)d_in[1];
    const float* fc_b  = (const float*)d_in[2];
    const float* bi_w  = (const float*)d_in[3];
    const float* bias  = (const float*)d_in[4];

    char* ws = (char*)d_ws;
    bf16_t* wbi = (bf16_t*)(ws);             // 3072*256*2 = 1,572,864
    bf16_t* t   = (bf16_t*)(ws + 1572864);   // 8192*256*2 = 4,194,304
    bf16_t* bl  = (bf16_t*)(ws + 5767168);   // 8192*3072*2 = 50,331,648

    // Front-end: bi_w cvt (384 blocks) + GEMM1 w/ fused A,B cvt (256 blocks)
    frontend<<<dim3(640), dim3(256), 0, stream>>>(
        input, fc_w, fc_b, bi_w, wbi, t);

    // GEMM2: bl = t @ wbi^T + bias[col&255]  (8-phase 256^2; 384 blocks)
    gemm8p<2, 0, 32, 12><<<dim3(384), dim3(512), 131072, stream>>>(
        t, wbi, (void*)bl, bias, 3072, 0L, 0L, 0L);

    // GEMM3 (batched x8): 192x128 tile, 4096 blocks, 2/CU, NT stores
    gemm3k<8><<<dim3(4096), dim3(256), 81920, stream>>>(
        bl, t, (float*)d_out,
        (long)12288 * 256, (long)1024 * 256, (long)12288 * 1024);
}